// Round 10
// baseline (288.452 us; speedup 1.0000x reference)
//
#include <hip/hip_runtime.h>
#include <hip/hip_fp16.h>

// Self-attention B=8 S=2048 D=512, fp32-vs-bf16 input auto-detect.
// R18 = R17 resubmit (container infra died twice before verification;
// source re-audited: triple-buffer overwrite ledger race-free, vmcnt
// counts exact, uniform barriers, LDS 144KB, u32 offsets in range).
// R17 = R15 (274.7 us best) restored exactly (R16's LDS-transposed fp32
// epilogue REGRESSED scores 56->62us; reverted), plus ONE experiment:
// PV moves to a corrected 8-phase kernel in its proper regime (K=2048,
// nt=32 -- proj/scores at nt=8 regressed in R11 and stay on the m97 loop).
// vs R11: triple-buffered LDS (144KB, 1 blk/CU) so the stage of tile t+2
// is SPREAD 2 gl16/phase across tile t (m196: burst-at-boundary hurts).
// Race-free: buf[(t+2)%3] readers finished at tile t-1's lgkm0+barrier.
// Counted vmcnt(6) only at tile boundaries. Frag/stage/epilogue formulas
// verbatim from R11 (harness-verified).
// History: R13 xy-swizzle +10; R14 proj transpose +10; R15 z-fold FETCH
// win; R9/R11/R12/R16 experiments reverted after measured regressions.

typedef unsigned short u16;
typedef unsigned int u32;
typedef __attribute__((ext_vector_type(8))) _Float16 f16x8;
typedef __attribute__((ext_vector_type(16))) float f32x16;
typedef __attribute__((ext_vector_type(4))) float f32x4;

#define S_LEN 2048
#define D_DIM 512
#define B_N 8

__device__ __forceinline__ u16 f2bf(float f) {
    u32 u = __float_as_uint(f);
    u32 r = u + 0x7FFFu + ((u >> 16) & 1u);   // RNE
    return (u16)(r >> 16);
}
__device__ __forceinline__ float bf2f(u16 h) {
    return __uint_as_float((u32)h << 16);
}
__device__ __forceinline__ u16 f2h(float f) {
    _Float16 h = (_Float16)f;                 // RNE
    return *(u16*)&h;
}
__device__ __forceinline__ void gl16(const u16* g, u16* l) {
    __builtin_amdgcn_global_load_lds(
        (const __attribute__((address_space(1))) void*)g,
        (__attribute__((address_space(3))) void*)l, 16, 0, 0);
}
__device__ __forceinline__ f32x16 mfma16(f16x8 a, f16x8 b, f32x16 c) {
    return __builtin_amdgcn_mfma_f32_32x32x16_f16(a, b, c, 0, 0, 0);
}
__device__ __forceinline__ f32x4 mfma16q(f16x8 a, f16x8 b, f32x4 c) {
    return __builtin_amdgcn_mfma_f32_16x16x32_f16(a, b, c, 0, 0, 0);
}

// ---- dtype detector ----
__global__ void detect_k(const u16* __restrict__ x, int* __restrict__ flag)
{
    int t = threadIdx.x;
    u16 u = x[2 * t];
    int e = (u >> 7) & 0xFF;
    int sane = (e == 0) || (e >= 110 && e <= 140);
    unsigned long long b = __ballot(sane);
    if (t == 0) *flag = (__popcll(b) >= 32) ? 1 : 0;
}

// ---- convert x to fp16 ----
__global__ __launch_bounds__(256) void cvt_x(
    const void* __restrict__ X, u16* __restrict__ xf,
    const int* __restrict__ flagp)
{
    const size_t i4 = ((size_t)blockIdx.x * 256 + threadIdx.x) * 4;
    float f[4];
    if (*flagp) {
        ushort4 u = *(const ushort4*)((const u16*)X + i4);
        f[0] = bf2f(u.x); f[1] = bf2f(u.y); f[2] = bf2f(u.z); f[3] = bf2f(u.w);
    } else {
        float4 ff = *(const float4*)((const float*)X + i4);
        f[0] = ff.x; f[1] = ff.y; f[2] = ff.z; f[3] = ff.w;
    }
    ushort4 h;
    h.x = f2h(f[0]); h.y = f2h(f[1]); h.z = f2h(f[2]); h.w = f2h(f[3]);
    *(ushort4*)(xf + i4) = h;
}

// ---- pack W^T concat (q|k|v) fp16: WT[n 0..1535][k 0..511] ----
__global__ __launch_bounds__(256) void pack_w(
    const void* __restrict__ Wq, const void* __restrict__ Wk, const void* __restrict__ Wv,
    u16* __restrict__ WT, const int* __restrict__ flagp)
{
    const int k = blockIdx.x;
    const int n = blockIdx.y * 256 + threadIdx.x;
    const void* W = n < 512 ? Wq : n < 1024 ? Wk : Wv;
    const int nc = n & 511;
    float f = *flagp ? bf2f(((const u16*)W)[(size_t)k * 512 + nc])
                     : ((const float*)W)[(size_t)k * 512 + nc];
    WT[(size_t)n * 512 + k] = f2h(f);
}

__global__ void pack_bias(
    const void* __restrict__ bq, const void* __restrict__ bk, const void* __restrict__ bv,
    float* __restrict__ bcat, const int* __restrict__ flagp)
{
    const int t = blockIdx.x * 256 + threadIdx.x;
    const void* b = t < 512 ? bq : t < 1024 ? bk : bv;
    const int i = t & 511;
    bcat[t] = *flagp ? bf2f(((const u16*)b)[i]) : ((const float*)b)[i];
}

// ---- unified fp16 BT-GEMM: C[M,N] = A[M,K] * B[N,K]^T ----
// 128x128 tile, BK=64. Staging: slot s of row r holds global chunk s^(r&7).
// EPI 0: z-fold chunked XCD swizzle, fp32 C (scores). EPI 2: identity map,
// proj q|k|vT(+LDS transpose) +bias. (EPI1 path retired -> gemm8pv.)
template <int EPI>
__global__ __launch_bounds__(256) void gemm_f16(
    const u16* __restrict__ A_, const u16* __restrict__ B_,
    void* __restrict__ Cp, const float* __restrict__ biasf,
    u16* __restrict__ Oq, u16* __restrict__ Ok, u16* __restrict__ OvT,
    const int* __restrict__ flagp,
    int K, int lda, int ldb, int ldc, long sA, long sB, long sC, long cbase)
{
    const int tid = threadIdx.x;
    const int lane = tid & 63, wav = tid >> 6;
    const int l31 = lane & 31, lh = lane >> 5;

    int bx, by, bz;
    if constexpr (EPI != 2) {
        // ---- XCD-aware chunked swizzle of the z-major linear id ----
        const int gx = gridDim.x, gy = gridDim.y;
        const int total = gx * gy * gridDim.z;
        const int chunk = total >> 3;              // total % 8 == 0
        int lin = (blockIdx.z * gy + blockIdx.y) * gx + blockIdx.x;
        lin = (lin & 7) * chunk + (lin >> 3);
        bx = lin % gx;
        by = (lin / gx) % gy;
        bz = lin / (gx * gy);
    } else {
        bx = blockIdx.x; by = blockIdx.y; bz = blockIdx.z;
    }

    const int m0 = by * 128, n0 = bx * 128;
    const int bm = (wav >> 1) * 64, bn = (wav & 1) * 64;

    const u16* A = A_ + (size_t)bz * sA;
    const u16* B = B_ + (size_t)bz * sB;

    // 32 KiB union: K-loop uses As|Bs halves; EPI2 v-mode reuses all of it
    // as a 128x128 fp16 transpose buffer after the final barrier.
    __shared__ __align__(16) u16 sh[16384];
    u16* As = sh;
    u16* Bs = sh + 8192;

    const int r0 = tid >> 3;
    const int c0 = ((tid & 7) ^ (r0 & 7)) * 8;
    size_t aoff[4], boff[4];
#pragma unroll
    for (int j = 0; j < 4; j++) {
        aoff[j] = (size_t)(m0 + r0 + j * 32) * lda + c0;
        boff[j] = (size_t)(n0 + r0 + j * 32) * ldb + c0;
    }
    const int g7 = l31 & 7;
    const int rowA0 = (bm + l31) * 64, rowA1 = (bm + 32 + l31) * 64;
    const int rowB0 = (bn + l31) * 64, rowB1 = (bn + 32 + l31) * 64;

    f32x16 acc[2][2];
#pragma unroll
    for (int i = 0; i < 2; i++)
#pragma unroll
        for (int j = 0; j < 2; j++)
#pragma unroll
            for (int r = 0; r < 16; r++) acc[i][j][r] = 0.f;

    for (int k0 = 0; k0 < K; k0 += 64) {
#pragma unroll
        for (int j = 0; j < 4; j++) {
            gl16(A + aoff[j] + k0, As + j * 2048 + wav * 512);
            gl16(B + boff[j] + k0, Bs + j * 2048 + wav * 512);
        }
        __syncthreads();

#pragma unroll
        for (int h = 0; h < 4; h++) {
            const int so = ((h * 2 + lh) ^ g7) * 8;
            f16x8 af[2], bfr[2];
            af[0] = *(const f16x8*)&As[rowA0 + so];
            af[1] = *(const f16x8*)&As[rowA1 + so];
            bfr[0] = *(const f16x8*)&Bs[rowB0 + so];
            bfr[1] = *(const f16x8*)&Bs[rowB1 + so];
#pragma unroll
            for (int i = 0; i < 2; i++)
#pragma unroll
                for (int j = 0; j < 2; j++)
                    acc[i][j] = mfma16(af[i], bfr[j], acc[i][j]);
        }
        __syncthreads();
    }

    // ---- epilogue: 32x32 C/D layout col=lane&31, row=(r&3)+8*(r>>2)+4*lh ----
    if (EPI == 2) {
        const int mode = bx >> 2;   // 0=q 1=k 2=v
        if (mode == 2) {
            // v: transpose 128x128 tile through LDS, coalesced vT stores.
#pragma unroll
            for (int it = 0; it < 2; it++)
#pragma unroll
                for (int jt = 0; jt < 2; jt++) {
                    const int lc = bn + jt * 32 + l31;          // 0..127
                    const float badd = biasf[n0 + lc];
#pragma unroll
                    for (int r = 0; r < 16; r++) {
                        const int row = bm + it * 32 + (r & 3) + 8 * (r >> 2) + 4 * lh;
                        sh[lc * 128 + (row ^ ((lc & 15) << 3))] =
                            f2h(acc[it][jt][r] + badd);
                    }
                }
            __syncthreads();
            const int vbase = n0 - 1024;                        // v col offset
#pragma unroll
            for (int p = 0; p < 8; p++) {
                const int q = p * 256 + tid;                    // 0..2047
                const int lc = q >> 4, ch = q & 15;
                const int g = ch ^ (lc & 15);
                f16x8 val = *(const f16x8*)&sh[lc * 128 + g * 8];
                *(f16x8*)&OvT[(size_t)(vbase + lc) * 16384 + m0 + ch * 8] = val;
            }
        } else {
#pragma unroll
            for (int it = 0; it < 2; it++)
#pragma unroll
                for (int jt = 0; jt < 2; jt++) {
                    const int gcol = n0 + bn + jt * 32 + l31;
                    const int lcol = gcol & 511;
                    const float badd = biasf[gcol];
#pragma unroll
                    for (int r = 0; r < 16; r++) {
                        const int row = m0 + bm + it * 32 + (r & 3) + 8 * (r >> 2) + 4 * lh;
                        const float v = acc[it][jt][r] + badd;
                        if (mode == 0) Oq[(size_t)row * 512 + lcol] = f2h(v);
                        else           Ok[(size_t)row * 512 + lcol] = f2h(v);
                    }
                }
        }
    } else {
        float* Cf = (float*)Cp;
        const long coff = (long)bz * sC;
#pragma unroll
        for (int it = 0; it < 2; it++)
#pragma unroll
            for (int jt = 0; jt < 2; jt++) {
                const int col = n0 + bn + jt * 32 + l31;
#pragma unroll
                for (int r = 0; r < 16; r++) {
                    const int row = m0 + bm + it * 32 + (r & 3) + 8 * (r >> 2) + 4 * lh;
                    Cf[(size_t)(coff + (long)row * ldc + col)] = acc[it][jt][r];
                }
            }
    }
}

// ---- 8-phase PV GEMM: C[M,N] = P[M,K] * vT[N,K]^T, K=2048 (nt=32) ----
// BM=256, BN=128, BK=64, 512 thr = 8 waves (2M x 4N), 16x16x32 MFMA.
// Triple-buffered LDS (144KB, 1 blk/CU): stage of tile t+2 spread 2 gl16
// per phase across tile t; counted vmcnt(6) at tile boundaries only.
// Frag/stage/epilogue formulas from the harness-verified R11 kernel.
__global__ __launch_bounds__(512, 1) void gemm8pv(
    const u16* __restrict__ A_, const u16* __restrict__ B_,
    void* __restrict__ Cp, const int* __restrict__ flagp,
    int K, int lda, int ldb, int ldc, long sA, long sB, long sC, long cbase)
{
    const int tid = threadIdx.x;
    const int lane = tid & 63;
    const int wid = tid >> 6;            // 0..7
    const int wm = wid >> 2;             // 0..1  (M half: 128 rows)
    const int wn = wid & 3;              // 0..3  (N quarter: 32 cols)
    const int l15 = lane & 15, lq = lane >> 4;
    const int colB = wn * 32;

    // z-fold chunked XCD swizzle (total = 32c, % 8 == 0 for c in {1,2,4,8})
    const int gx = gridDim.x, gy = gridDim.y;
    const int total = gx * gy * gridDim.z;
    const int chunk = total >> 3;
    int lin = (blockIdx.z * gy + blockIdx.y) * gx + blockIdx.x;
    lin = (lin & 7) * chunk + (lin >> 3);
    const int bx = lin % gx;
    const int by = (lin / gx) % gy;
    const int bz = lin / (gx * gy);

    const int m0 = by * 256, n0 = bx * 128;

    const u16* A = A_ + (size_t)bz * sA;
    const u16* B = B_ + (size_t)bz * sB;

    __shared__ __align__(16) u16 As[3][256 * 64];   // 3 x 32 KiB
    __shared__ __align__(16) u16 Bs[3][128 * 64];   // 3 x 16 KiB

    // staging: thread t loads 16B; row r0 = t>>3, slot t&7 holds chunk c0/8
    const int r0 = tid >> 3;                       // 0..63
    const int c0 = ((tid & 7) ^ (r0 & 7)) * 8;     // pre-swizzled source col
    u32 aoffs[4], boffs[2];
#pragma unroll
    for (int j = 0; j < 4; j++)
        aoffs[j] = (u32)((m0 + j * 64 + r0) * lda + c0);
#pragma unroll
    for (int j = 0; j < 2; j++)
        boffs[j] = (u32)((n0 + j * 64 + r0) * ldb + c0);
    const int stageDst = wid << 9;                 // wave-uniform LDS elems

    const int nt = K >> 6;                         // 32

    f32x4 acc[8][2];
#pragma unroll
    for (int mi = 0; mi < 8; mi++)
#pragma unroll
        for (int nj = 0; nj < 2; nj++)
#pragma unroll
            for (int r = 0; r < 4; r++) acc[mi][nj][r] = 0.f;

    auto stage6 = [&](u16* dA, u16* dB, int k0) {
#pragma unroll
        for (int j = 0; j < 4; j++)
            gl16(A + aoffs[j] + k0, dA + (j << 12) + stageDst);
#pragma unroll
        for (int j = 0; j < 2; j++)
            gl16(B + boffs[j] + k0, dB + (j << 12) + stageDst);
    };
    auto rdA = [&](const u16* buf, int p, int h, int ks) -> f16x8 {
        const int row = (wm << 7) + (p << 5) + (h << 4) + l15;
        const int off = (row << 6) + ((((ks << 2) + lq) ^ (row & 7)) << 3);
        return *(const f16x8*)(buf + off);
    };
    auto rdB = [&](const u16* buf, int nj, int ks) -> f16x8 {
        const int row = colB + (nj << 4) + l15;
        const int off = (row << 6) + ((((ks << 2) + lq) ^ (row & 7)) << 3);
        return *(const f16x8*)(buf + off);
    };

    // prologue: stage tiles 0 and 1 fully; counted wait for tile 0.
    stage6(As[0], Bs[0], 0);
    stage6(As[1], Bs[1], 64);
    asm volatile("s_waitcnt vmcnt(6)" ::: "memory");
    __builtin_amdgcn_sched_barrier(0);
    __builtin_amdgcn_s_barrier();

    for (int tt = 0; tt < nt; tt++) {
        const int bi = tt % 3, si = (tt + 2) % 3;
        const u16* Ab = As[bi];
        const u16* Bb = Bs[bi];
        u16* dA = As[si];
        u16* dB = Bs[si];
        const bool doStage = (tt + 2 < nt);
        const int k2 = (tt + 2) * 64;
        f16x8 bfr[2][2];
#pragma unroll
        for (int p = 0; p < 4; p++) {
            if (p == 0) {
#pragma unroll
                for (int nj = 0; nj < 2; nj++)
#pragma unroll
                    for (int ks = 0; ks < 2; ks++)
                        bfr[nj][ks] = rdB(Bb, nj, ks);
            }
            f16x8 a[2][2];
#pragma unroll
            for (int h = 0; h < 2; h++)
#pragma unroll
                for (int ks = 0; ks < 2; ks++)
                    a[h][ks] = rdA(Ab, p, h, ks);
            // spread stage: 2 gl16 per phase (p=0,1: A halves; p=2: B)
            if (doStage) {
                if (p == 0) {
                    gl16(A + aoffs[0] + k2, dA + stageDst);
                    gl16(A + aoffs[1] + k2, dA + (1 << 12) + stageDst);
                } else if (p == 1) {
                    gl16(A + aoffs[2] + k2, dA + (2 << 12) + stageDst);
                    gl16(A + aoffs[3] + k2, dA + (3 << 12) + stageDst);
                } else if (p == 2) {
                    gl16(B + boffs[0] + k2, dB + stageDst);
                    gl16(B + boffs[1] + k2, dB + (1 << 12) + stageDst);
                }
            }
            if (p == 3) {
                // all our LDS reads of this buffer must be IN REGISTERS
                // before any wave overwrites it (staging during tile tt+1).
                asm volatile("s_waitcnt lgkmcnt(0)" ::: "memory");
                __builtin_amdgcn_sched_barrier(0);
            }
            __builtin_amdgcn_s_barrier();
            __builtin_amdgcn_s_setprio(1);
#pragma unroll
            for (int h = 0; h < 2; h++)
#pragma unroll
                for (int nj = 0; nj < 2; nj++)
#pragma unroll
                    for (int ks = 0; ks < 2; ks++)
                        acc[2 * p + h][nj] =
                            mfma16q(a[h][ks], bfr[nj][ks], acc[2 * p + h][nj]);
            __builtin_amdgcn_s_setprio(0);
            if (p < 3) {
                __builtin_amdgcn_s_barrier();
            } else if (tt + 1 < nt) {
                // boundary: tile tt+1's 6 loads landed; tt+2's may fly on.
                if (tt + 2 < nt)
                    asm volatile("s_waitcnt vmcnt(6)" ::: "memory");
                else
                    asm volatile("s_waitcnt vmcnt(0)" ::: "memory");
                __builtin_amdgcn_sched_barrier(0);
                __builtin_amdgcn_s_barrier();
            }
        }
    }

    // ---- epilogue: 16x16 C/D layout col=lane&15, row=(lane>>4)*4+reg ----
    const int isbf = *flagp;
    float* Cf = (float*)Cp;
    u16* Cb = (u16*)Cp;
    const long coff = cbase + (long)bz * sC;
#pragma unroll
    for (int nj = 0; nj < 2; nj++) {
        const int col = n0 + colB + nj * 16 + l15;
#pragma unroll
        for (int mi = 0; mi < 8; mi++)
#pragma unroll
            for (int r = 0; r < 4; r++) {
                const int row = m0 + (wm << 7) + mi * 16 + lq * 4 + r;
                const size_t idx = (size_t)(coff + (long)row * ldc + col);
                if (isbf) Cb[idx] = f2bf(acc[mi][nj][r]);
                else Cf[idx] = acc[mi][nj][r];
            }
    }
}

// ---- softmax: fp32 row -> fp16 P in place (first half of row bytes) ----
__global__ __launch_bounds__(256) void softmax_k(float* __restrict__ sc)
{
    float* srow = sc + (size_t)blockIdx.x * S_LEN;
    const int tid = threadIdx.x;

    float4 a = ((const float4*)srow)[tid];
    float4 b = ((const float4*)srow)[256 + tid];

    float m = fmaxf(fmaxf(fmaxf(a.x, a.y), fmaxf(a.z, a.w)),
                    fmaxf(fmaxf(b.x, b.y), fmaxf(b.z, b.w)));
#pragma unroll
    for (int off = 32; off > 0; off >>= 1) m = fmaxf(m, __shfl_down(m, off));

    __shared__ float redm[4], reds[4];
    if ((tid & 63) == 0) redm[tid >> 6] = m;
    __syncthreads();
    m = fmaxf(fmaxf(redm[0], redm[1]), fmaxf(redm[2], redm[3]));

    a.x = __expf(a.x - m); a.y = __expf(a.y - m);
    a.z = __expf(a.z - m); a.w = __expf(a.w - m);
    b.x = __expf(b.x - m); b.y = __expf(b.y - m);
    b.z = __expf(b.z - m); b.w = __expf(b.w - m);
    float s = a.x + a.y + a.z + a.w + b.x + b.y + b.z + b.w;
#pragma unroll
    for (int off = 32; off > 0; off >>= 1) s += __shfl_down(s, off);
    if ((tid & 63) == 0) reds[tid >> 6] = s;
    __syncthreads();
    s = reds[0] + reds[1] + reds[2] + reds[3];

    const float inv = 1.0f / s;
    ushort4 pa, pb;
    pa.x = f2h(a.x * inv); pa.y = f2h(a.y * inv);
    pa.z = f2h(a.z * inv); pa.w = f2h(a.w * inv);
    pb.x = f2h(b.x * inv); pb.y = f2h(b.y * inv);
    pb.z = f2h(b.z * inv); pb.w = f2h(b.w * inv);
    ((ushort4*)srow)[tid] = pa;
    ((ushort4*)srow)[256 + tid] = pb;
}

extern "C" void kernel_launch(void* const* d_in, const int* in_sizes, int n_in,
                              void* d_out, int out_size, void* d_ws, size_t ws_size,
                              hipStream_t stream)
{
    const void* x  = d_in[0];
    const void* Wq = d_in[1]; const void* bq = d_in[2];
    const void* Wk = d_in[3]; const void* bk = d_in[4];
    const void* Wv = d_in[5]; const void* bv = d_in[6];

    const int S = S_LEN, D = D_DIM;
    const long SD = (long)S * D;                      // 1,048,576

    char* w = (char*)d_ws;
    int*   flag = (int*)w;                            // @0
    u16*   WT   = (u16*)(w + 1024);                   // 1,572,864
    float* bcat = (float*)(w + 1573888);              // 6,144
    u16*   xf   = (u16*)(w + 1580032);                // 16,777,216
    u16*   qf   = (u16*)(w + 18357248);
    u16*   kf   = (u16*)(w + 35134464);
    u16*   vT   = (u16*)(w + 51911680);               // [512][16384]
    float* scA  = (float*)(w + 68688896);             // scores arena

    const size_t avail = ws_size > 68688896ull ? ws_size - 68688896ull : 0;
    const size_t perb = (size_t)S * S * 4;
    const int c = avail >= 8 * perb ? 8 : avail >= 4 * perb ? 4 : avail >= 2 * perb ? 2 : 1;

    dim3 blk(256), blk5(512);

    detect_k<<<1, 64, 0, stream>>>((const u16*)x, flag);
    cvt_x<<<8192, blk, 0, stream>>>(x, xf, flag);
    pack_w<<<dim3(512, 6), blk, 0, stream>>>(Wq, Wk, Wv, WT, flag);
    pack_bias<<<6, blk, 0, stream>>>(bq, bk, bv, bcat, flag);

    // fused q|k|v projection: [16384,512] x [512,1536]^T(packed WT)
    gemm_f16<2><<<dim3(12, 128, 1), blk, 0, stream>>>(
        xf, WT, nullptr, bcat, qf, kf, vT, flag,
        512, 512, 512, 0, 0, 0, 0, 0);

    for (int cb = 0; cb < B_N; cb += c) {
        const size_t off = (size_t)cb * SD;
        // scores = q k^T (fp32)
        gemm_f16<0><<<dim3(16, 16, c), blk, 0, stream>>>(
            qf + off, kf + off, scA, nullptr, nullptr, nullptr, nullptr, flag,
            512, 512, 512, S, SD, SD, (long)S * S, 0);
        softmax_k<<<c * S, blk, 0, stream>>>(scA);
        // out = P @ v via vT rows; P fp16 over fp32 rows (lda = 2S); 8-phase
        gemm8pv<<<dim3(4, 8, c), blk5, 0, stream>>>(
            (const u16*)scA, vT + (size_t)cb * S, d_out, flag,
            S, 2 * S, B_N * S, D, 2ll * S * S, S, SD, (long)cb * SD);
    }
}

// Round 11
// 273.971 us; speedup vs baseline: 1.0529x; 1.0529x over previous
//
#include <hip/hip_runtime.h>
#include <hip/hip_fp16.h>

// Self-attention B=8 S=2048 D=512, fp32-vs-bf16 input auto-detect.
// R19 = R15 (274.7 us measured best) with PV reverted to the m97-loop
// (R18's corrected 8-phase PV regressed 61us vs ~55: the 8-phase line is
// closed -- R9/R11/R12/R18 all lost to the simple 2-barrier loop), plus
// ONE retest: z-fold swizzle now also on proj (EPI2). R13's "swizzle
// hurts proj" measurement was confounded by the v-scatter store (fixed in
// R14): post-fix proj shows FETCH 84MB vs 18MB ideal; chunked z-fold
// gives each XCD 16 contiguous xf row-panels (2MB) + all WT (1.5MB) = L2
// resident. total=1536 %8==0; mode uses logical bx (semantics unchanged).
// History: R13 xy-swizzle +10; R14 proj v-transpose +10; R15 z-fold FETCH
// win; R9/R11/R12/R16/R18 experiments reverted after measured regressions.

typedef unsigned short u16;
typedef unsigned int u32;
typedef __attribute__((ext_vector_type(8))) _Float16 f16x8;
typedef __attribute__((ext_vector_type(16))) float f32x16;

#define S_LEN 2048
#define D_DIM 512
#define B_N 8

__device__ __forceinline__ u16 f2bf(float f) {
    u32 u = __float_as_uint(f);
    u32 r = u + 0x7FFFu + ((u >> 16) & 1u);   // RNE
    return (u16)(r >> 16);
}
__device__ __forceinline__ float bf2f(u16 h) {
    return __uint_as_float((u32)h << 16);
}
__device__ __forceinline__ u16 f2h(float f) {
    _Float16 h = (_Float16)f;                 // RNE
    return *(u16*)&h;
}
__device__ __forceinline__ void gl16(const u16* g, u16* l) {
    __builtin_amdgcn_global_load_lds(
        (const __attribute__((address_space(1))) void*)g,
        (__attribute__((address_space(3))) void*)l, 16, 0, 0);
}
__device__ __forceinline__ f32x16 mfma16(f16x8 a, f16x8 b, f32x16 c) {
    return __builtin_amdgcn_mfma_f32_32x32x16_f16(a, b, c, 0, 0, 0);
}

// ---- dtype detector ----
__global__ void detect_k(const u16* __restrict__ x, int* __restrict__ flag)
{
    int t = threadIdx.x;
    u16 u = x[2 * t];
    int e = (u >> 7) & 0xFF;
    int sane = (e == 0) || (e >= 110 && e <= 140);
    unsigned long long b = __ballot(sane);
    if (t == 0) *flag = (__popcll(b) >= 32) ? 1 : 0;
}

// ---- convert x to fp16 ----
__global__ __launch_bounds__(256) void cvt_x(
    const void* __restrict__ X, u16* __restrict__ xf,
    const int* __restrict__ flagp)
{
    const size_t i4 = ((size_t)blockIdx.x * 256 + threadIdx.x) * 4;
    float f[4];
    if (*flagp) {
        ushort4 u = *(const ushort4*)((const u16*)X + i4);
        f[0] = bf2f(u.x); f[1] = bf2f(u.y); f[2] = bf2f(u.z); f[3] = bf2f(u.w);
    } else {
        float4 ff = *(const float4*)((const float*)X + i4);
        f[0] = ff.x; f[1] = ff.y; f[2] = ff.z; f[3] = ff.w;
    }
    ushort4 h;
    h.x = f2h(f[0]); h.y = f2h(f[1]); h.z = f2h(f[2]); h.w = f2h(f[3]);
    *(ushort4*)(xf + i4) = h;
}

// ---- pack W^T concat (q|k|v) fp16: WT[n 0..1535][k 0..511] ----
__global__ __launch_bounds__(256) void pack_w(
    const void* __restrict__ Wq, const void* __restrict__ Wk, const void* __restrict__ Wv,
    u16* __restrict__ WT, const int* __restrict__ flagp)
{
    const int k = blockIdx.x;
    const int n = blockIdx.y * 256 + threadIdx.x;
    const void* W = n < 512 ? Wq : n < 1024 ? Wk : Wv;
    const int nc = n & 511;
    float f = *flagp ? bf2f(((const u16*)W)[(size_t)k * 512 + nc])
                     : ((const float*)W)[(size_t)k * 512 + nc];
    WT[(size_t)n * 512 + k] = f2h(f);
}

__global__ void pack_bias(
    const void* __restrict__ bq, const void* __restrict__ bk, const void* __restrict__ bv,
    float* __restrict__ bcat, const int* __restrict__ flagp)
{
    const int t = blockIdx.x * 256 + threadIdx.x;
    const void* b = t < 512 ? bq : t < 1024 ? bk : bv;
    const int i = t & 511;
    bcat[t] = *flagp ? bf2f(((const u16*)b)[i]) : ((const float*)b)[i];
}

// ---- unified fp16 BT-GEMM: C[M,N] = A[M,K] * B[N,K]^T ----
// 128x128 tile, BK=64. Staging: slot s of row r holds global chunk s^(r&7).
// z-fold chunked XCD swizzle on ALL paths (total%8==0 at all call sites).
// EPI 0: fp32 C (scores). EPI 1: flag-dtyped C (out). EPI 2: proj q|k|vT +bias.
template <int EPI>
__global__ __launch_bounds__(256) void gemm_f16(
    const u16* __restrict__ A_, const u16* __restrict__ B_,
    void* __restrict__ Cp, const float* __restrict__ biasf,
    u16* __restrict__ Oq, u16* __restrict__ Ok, u16* __restrict__ OvT,
    const int* __restrict__ flagp,
    int K, int lda, int ldb, int ldc, long sA, long sB, long sC, long cbase)
{
    const int tid = threadIdx.x;
    const int lane = tid & 63, wav = tid >> 6;
    const int l31 = lane & 31, lh = lane >> 5;

    // ---- XCD-aware chunked swizzle of the z-major linear id ----
    const int gx = gridDim.x, gy = gridDim.y;
    const int total = gx * gy * gridDim.z;
    const int chunk = total >> 3;              // total % 8 == 0
    int lin = (blockIdx.z * gy + blockIdx.y) * gx + blockIdx.x;
    lin = (lin & 7) * chunk + (lin >> 3);
    const int bx = lin % gx;
    const int by = (lin / gx) % gy;
    const int bz = lin / (gx * gy);

    const int m0 = by * 128, n0 = bx * 128;
    const int bm = (wav >> 1) * 64, bn = (wav & 1) * 64;

    const u16* A = A_ + (size_t)bz * sA;
    const u16* B = B_ + (size_t)bz * sB;

    // 32 KiB union: K-loop uses As|Bs halves; EPI2 v-mode reuses all of it
    // as a 128x128 fp16 transpose buffer after the final barrier.
    __shared__ __align__(16) u16 sh[16384];
    u16* As = sh;
    u16* Bs = sh + 8192;

    const int r0 = tid >> 3;
    const int c0 = ((tid & 7) ^ (r0 & 7)) * 8;
    size_t aoff[4], boff[4];
#pragma unroll
    for (int j = 0; j < 4; j++) {
        aoff[j] = (size_t)(m0 + r0 + j * 32) * lda + c0;
        boff[j] = (size_t)(n0 + r0 + j * 32) * ldb + c0;
    }
    const int g7 = l31 & 7;
    const int rowA0 = (bm + l31) * 64, rowA1 = (bm + 32 + l31) * 64;
    const int rowB0 = (bn + l31) * 64, rowB1 = (bn + 32 + l31) * 64;

    f32x16 acc[2][2];
#pragma unroll
    for (int i = 0; i < 2; i++)
#pragma unroll
        for (int j = 0; j < 2; j++)
#pragma unroll
            for (int r = 0; r < 16; r++) acc[i][j][r] = 0.f;

    for (int k0 = 0; k0 < K; k0 += 64) {
#pragma unroll
        for (int j = 0; j < 4; j++) {
            gl16(A + aoff[j] + k0, As + j * 2048 + wav * 512);
            gl16(B + boff[j] + k0, Bs + j * 2048 + wav * 512);
        }
        __syncthreads();

#pragma unroll
        for (int h = 0; h < 4; h++) {
            const int so = ((h * 2 + lh) ^ g7) * 8;
            f16x8 af[2], bfr[2];
            af[0] = *(const f16x8*)&As[rowA0 + so];
            af[1] = *(const f16x8*)&As[rowA1 + so];
            bfr[0] = *(const f16x8*)&Bs[rowB0 + so];
            bfr[1] = *(const f16x8*)&Bs[rowB1 + so];
#pragma unroll
            for (int i = 0; i < 2; i++)
#pragma unroll
                for (int j = 0; j < 2; j++)
                    acc[i][j] = mfma16(af[i], bfr[j], acc[i][j]);
        }
        __syncthreads();
    }

    // ---- epilogue: 32x32 C/D layout col=lane&31, row=(r&3)+8*(r>>2)+4*lh ----
    if (EPI == 2) {
        const int mode = bx >> 2;   // 0=q 1=k 2=v (logical bx)
        if (mode == 2) {
            // v: transpose 128x128 tile through LDS, coalesced vT stores.
#pragma unroll
            for (int it = 0; it < 2; it++)
#pragma unroll
                for (int jt = 0; jt < 2; jt++) {
                    const int lc = bn + jt * 32 + l31;          // 0..127
                    const float badd = biasf[n0 + lc];
#pragma unroll
                    for (int r = 0; r < 16; r++) {
                        const int row = bm + it * 32 + (r & 3) + 8 * (r >> 2) + 4 * lh;
                        sh[lc * 128 + (row ^ ((lc & 15) << 3))] =
                            f2h(acc[it][jt][r] + badd);
                    }
                }
            __syncthreads();
            const int vbase = n0 - 1024;                        // v col offset
#pragma unroll
            for (int p = 0; p < 8; p++) {
                const int q = p * 256 + tid;                    // 0..2047
                const int lc = q >> 4, ch = q & 15;
                const int g = ch ^ (lc & 15);
                f16x8 val = *(const f16x8*)&sh[lc * 128 + g * 8];
                *(f16x8*)&OvT[(size_t)(vbase + lc) * 16384 + m0 + ch * 8] = val;
            }
        } else {
#pragma unroll
            for (int it = 0; it < 2; it++)
#pragma unroll
                for (int jt = 0; jt < 2; jt++) {
                    const int gcol = n0 + bn + jt * 32 + l31;
                    const int lcol = gcol & 511;
                    const float badd = biasf[gcol];
#pragma unroll
                    for (int r = 0; r < 16; r++) {
                        const int row = m0 + bm + it * 32 + (r & 3) + 8 * (r >> 2) + 4 * lh;
                        const float v = acc[it][jt][r] + badd;
                        if (mode == 0) Oq[(size_t)row * 512 + lcol] = f2h(v);
                        else           Ok[(size_t)row * 512 + lcol] = f2h(v);
                    }
                }
        }
    } else if (EPI == 0) {
        float* Cf = (float*)Cp;
        const long coff = (long)bz * sC;
#pragma unroll
        for (int it = 0; it < 2; it++)
#pragma unroll
            for (int jt = 0; jt < 2; jt++) {
                const int col = n0 + bn + jt * 32 + l31;
#pragma unroll
                for (int r = 0; r < 16; r++) {
                    const int row = m0 + bm + it * 32 + (r & 3) + 8 * (r >> 2) + 4 * lh;
                    Cf[(size_t)(coff + (long)row * ldc + col)] = acc[it][jt][r];
                }
            }
    } else {
        const int isbf = *flagp;
        float* Cf = (float*)Cp;
        u16* Cb = (u16*)Cp;
        const long coff = cbase + (long)bz * sC;
#pragma unroll
        for (int it = 0; it < 2; it++)
#pragma unroll
            for (int jt = 0; jt < 2; jt++) {
                const int col = n0 + bn + jt * 32 + l31;
#pragma unroll
                for (int r = 0; r < 16; r++) {
                    const int row = m0 + bm + it * 32 + (r & 3) + 8 * (r >> 2) + 4 * lh;
                    const size_t idx = (size_t)(coff + (long)row * ldc + col);
                    if (isbf) Cb[idx] = f2bf(acc[it][jt][r]);
                    else Cf[idx] = acc[it][jt][r];
                }
            }
    }
}

// ---- softmax: fp32 row -> fp16 P in place (first half of row bytes) ----
__global__ __launch_bounds__(256) void softmax_k(float* __restrict__ sc)
{
    float* srow = sc + (size_t)blockIdx.x * S_LEN;
    const int tid = threadIdx.x;

    float4 a = ((const float4*)srow)[tid];
    float4 b = ((const float4*)srow)[256 + tid];

    float m = fmaxf(fmaxf(fmaxf(a.x, a.y), fmaxf(a.z, a.w)),
                    fmaxf(fmaxf(b.x, b.y), fmaxf(b.z, b.w)));
#pragma unroll
    for (int off = 32; off > 0; off >>= 1) m = fmaxf(m, __shfl_down(m, off));

    __shared__ float redm[4], reds[4];
    if ((tid & 63) == 0) redm[tid >> 6] = m;
    __syncthreads();
    m = fmaxf(fmaxf(redm[0], redm[1]), fmaxf(redm[2], redm[3]));

    a.x = __expf(a.x - m); a.y = __expf(a.y - m);
    a.z = __expf(a.z - m); a.w = __expf(a.w - m);
    b.x = __expf(b.x - m); b.y = __expf(b.y - m);
    b.z = __expf(b.z - m); b.w = __expf(b.w - m);
    float s = a.x + a.y + a.z + a.w + b.x + b.y + b.z + b.w;
#pragma unroll
    for (int off = 32; off > 0; off >>= 1) s += __shfl_down(s, off);
    if ((tid & 63) == 0) reds[tid >> 6] = s;
    __syncthreads();
    s = reds[0] + reds[1] + reds[2] + reds[3];

    const float inv = 1.0f / s;
    ushort4 pa, pb;
    pa.x = f2h(a.x * inv); pa.y = f2h(a.y * inv);
    pa.z = f2h(a.z * inv); pa.w = f2h(a.w * inv);
    pb.x = f2h(b.x * inv); pb.y = f2h(b.y * inv);
    pb.z = f2h(b.z * inv); pb.w = f2h(b.w * inv);
    ((ushort4*)srow)[tid] = pa;
    ((ushort4*)srow)[256 + tid] = pb;
}

extern "C" void kernel_launch(void* const* d_in, const int* in_sizes, int n_in,
                              void* d_out, int out_size, void* d_ws, size_t ws_size,
                              hipStream_t stream)
{
    const void* x  = d_in[0];
    const void* Wq = d_in[1]; const void* bq = d_in[2];
    const void* Wk = d_in[3]; const void* bk = d_in[4];
    const void* Wv = d_in[5]; const void* bv = d_in[6];

    const int S = S_LEN, D = D_DIM;
    const long SD = (long)S * D;                      // 1,048,576

    char* w = (char*)d_ws;
    int*   flag = (int*)w;                            // @0
    u16*   WT   = (u16*)(w + 1024);                   // 1,572,864
    float* bcat = (float*)(w + 1573888);              // 6,144
    u16*   xf   = (u16*)(w + 1580032);                // 16,777,216
    u16*   qf   = (u16*)(w + 18357248);
    u16*   kf   = (u16*)(w + 35134464);
    u16*   vT   = (u16*)(w + 51911680);               // [512][16384]
    float* scA  = (float*)(w + 68688896);             // scores arena

    const size_t avail = ws_size > 68688896ull ? ws_size - 68688896ull : 0;
    const size_t perb = (size_t)S * S * 4;
    const int c = avail >= 8 * perb ? 8 : avail >= 4 * perb ? 4 : avail >= 2 * perb ? 2 : 1;

    dim3 blk(256);

    detect_k<<<1, 64, 0, stream>>>((const u16*)x, flag);
    cvt_x<<<8192, blk, 0, stream>>>(x, xf, flag);
    pack_w<<<dim3(512, 6), blk, 0, stream>>>(Wq, Wk, Wv, WT, flag);
    pack_bias<<<6, blk, 0, stream>>>(bq, bk, bv, bcat, flag);

    // fused q|k|v projection: [16384,512] x [512,1536]^T(packed WT)
    gemm_f16<2><<<dim3(12, 128, 1), blk, 0, stream>>>(
        xf, WT, nullptr, bcat, qf, kf, vT, flag,
        512, 512, 512, 0, 0, 0, 0, 0);

    for (int cb = 0; cb < B_N; cb += c) {
        const size_t off = (size_t)cb * SD;
        // scores = q k^T (fp32)
        gemm_f16<0><<<dim3(16, 16, c), blk, 0, stream>>>(
            qf + off, kf + off, scA, nullptr, nullptr, nullptr, nullptr, flag,
            512, 512, 512, S, SD, SD, (long)S * S, 0);
        softmax_k<<<c * S, blk, 0, stream>>>(scA);
        // out = P @ v via vT rows; P fp16 over fp32 rows (lda = 2S)
        gemm_f16<1><<<dim3(4, 16, c), blk, 0, stream>>>(
            (const u16*)scA, vT + (size_t)cb * S, d_out, nullptr,
            nullptr, nullptr, nullptr, flag,
            S, 2 * S, B_N * S, D, 2ll * S * S, S, SD, (long)cb * SD);
    }
}

// Round 12
// 252.187 us; speedup vs baseline: 1.1438x; 1.0864x over previous
//
#include <hip/hip_runtime.h>
#include <hip/hip_fp16.h>

// Self-attention B=8 S=2048 D=512, fp32-vs-bf16 input auto-detect.
// R20 = R19 (274.0 us best) + fp16 score arena. R19 counters: scores is
// the sole top dispatch (55us), FETCH ideal (33MB), WRITE 134MB fp32 at
// 2.4 TB/s -- ~77% of the ~3.15 TB/s one-directional write ceiling implied
// by the 6.29 TB/s copy ubench. Remaining slack = mandatory bytes, not
// schedule. Fix: scores written fp16 (WRITE 134->67MB), softmax reads
// fp16 (134->67MB), P stays fp16 in place, PV reads compact lda=S.
// Precision: fp16 ulp at |s|~22-100 is 0.016-0.06 -> exp factor <=3% ->
// output delta ~0.03 vs existing 0.0625 absmax. If threshold trips,
// NEXT ROUND REVERTS TO R19 (verified fallback).
// History: R13 xy-swizzle +10; R14 proj v-transpose +10; R15/R19 z-fold
// swizzle; R9/R11/R12/R16/R18 schedule experiments all regressed->reverted.

typedef unsigned short u16;
typedef unsigned int u32;
typedef __attribute__((ext_vector_type(8))) _Float16 f16x8;
typedef __attribute__((ext_vector_type(16))) float f32x16;

#define S_LEN 2048
#define D_DIM 512
#define B_N 8

__device__ __forceinline__ u16 f2bf(float f) {
    u32 u = __float_as_uint(f);
    u32 r = u + 0x7FFFu + ((u >> 16) & 1u);   // RNE
    return (u16)(r >> 16);
}
__device__ __forceinline__ float bf2f(u16 h) {
    return __uint_as_float((u32)h << 16);
}
__device__ __forceinline__ u16 f2h(float f) {
    _Float16 h = (_Float16)f;                 // RNE
    return *(u16*)&h;
}
__device__ __forceinline__ float h2f(u16 h) {
    _Float16 v = *(_Float16*)&h;
    return (float)v;
}
__device__ __forceinline__ void gl16(const u16* g, u16* l) {
    __builtin_amdgcn_global_load_lds(
        (const __attribute__((address_space(1))) void*)g,
        (__attribute__((address_space(3))) void*)l, 16, 0, 0);
}
__device__ __forceinline__ f32x16 mfma16(f16x8 a, f16x8 b, f32x16 c) {
    return __builtin_amdgcn_mfma_f32_32x32x16_f16(a, b, c, 0, 0, 0);
}

// ---- dtype detector ----
__global__ void detect_k(const u16* __restrict__ x, int* __restrict__ flag)
{
    int t = threadIdx.x;
    u16 u = x[2 * t];
    int e = (u >> 7) & 0xFF;
    int sane = (e == 0) || (e >= 110 && e <= 140);
    unsigned long long b = __ballot(sane);
    if (t == 0) *flag = (__popcll(b) >= 32) ? 1 : 0;
}

// ---- convert x to fp16 ----
__global__ __launch_bounds__(256) void cvt_x(
    const void* __restrict__ X, u16* __restrict__ xf,
    const int* __restrict__ flagp)
{
    const size_t i4 = ((size_t)blockIdx.x * 256 + threadIdx.x) * 4;
    float f[4];
    if (*flagp) {
        ushort4 u = *(const ushort4*)((const u16*)X + i4);
        f[0] = bf2f(u.x); f[1] = bf2f(u.y); f[2] = bf2f(u.z); f[3] = bf2f(u.w);
    } else {
        float4 ff = *(const float4*)((const float*)X + i4);
        f[0] = ff.x; f[1] = ff.y; f[2] = ff.z; f[3] = ff.w;
    }
    ushort4 h;
    h.x = f2h(f[0]); h.y = f2h(f[1]); h.z = f2h(f[2]); h.w = f2h(f[3]);
    *(ushort4*)(xf + i4) = h;
}

// ---- pack W^T concat (q|k|v) fp16: WT[n 0..1535][k 0..511] ----
__global__ __launch_bounds__(256) void pack_w(
    const void* __restrict__ Wq, const void* __restrict__ Wk, const void* __restrict__ Wv,
    u16* __restrict__ WT, const int* __restrict__ flagp)
{
    const int k = blockIdx.x;
    const int n = blockIdx.y * 256 + threadIdx.x;
    const void* W = n < 512 ? Wq : n < 1024 ? Wk : Wv;
    const int nc = n & 511;
    float f = *flagp ? bf2f(((const u16*)W)[(size_t)k * 512 + nc])
                     : ((const float*)W)[(size_t)k * 512 + nc];
    WT[(size_t)n * 512 + k] = f2h(f);
}

__global__ void pack_bias(
    const void* __restrict__ bq, const void* __restrict__ bk, const void* __restrict__ bv,
    float* __restrict__ bcat, const int* __restrict__ flagp)
{
    const int t = blockIdx.x * 256 + threadIdx.x;
    const void* b = t < 512 ? bq : t < 1024 ? bk : bv;
    const int i = t & 511;
    bcat[t] = *flagp ? bf2f(((const u16*)b)[i]) : ((const float*)b)[i];
}

// ---- unified fp16 BT-GEMM: C[M,N] = A[M,K] * B[N,K]^T ----
// 128x128 tile, BK=64. Staging: slot s of row r holds global chunk s^(r&7).
// z-fold chunked XCD swizzle on ALL paths (total%8==0 at all call sites).
// EPI 0: fp16 C (scores, compact u16 arena). EPI 1: flag-dtyped C (out).
// EPI 2: proj q|k|vT(+LDS transpose) +bias.
template <int EPI>
__global__ __launch_bounds__(256) void gemm_f16(
    const u16* __restrict__ A_, const u16* __restrict__ B_,
    void* __restrict__ Cp, const float* __restrict__ biasf,
    u16* __restrict__ Oq, u16* __restrict__ Ok, u16* __restrict__ OvT,
    const int* __restrict__ flagp,
    int K, int lda, int ldb, int ldc, long sA, long sB, long sC, long cbase)
{
    const int tid = threadIdx.x;
    const int lane = tid & 63, wav = tid >> 6;
    const int l31 = lane & 31, lh = lane >> 5;

    // ---- XCD-aware chunked swizzle of the z-major linear id ----
    const int gx = gridDim.x, gy = gridDim.y;
    const int total = gx * gy * gridDim.z;
    const int chunk = total >> 3;              // total % 8 == 0
    int lin = (blockIdx.z * gy + blockIdx.y) * gx + blockIdx.x;
    lin = (lin & 7) * chunk + (lin >> 3);
    const int bx = lin % gx;
    const int by = (lin / gx) % gy;
    const int bz = lin / (gx * gy);

    const int m0 = by * 128, n0 = bx * 128;
    const int bm = (wav >> 1) * 64, bn = (wav & 1) * 64;

    const u16* A = A_ + (size_t)bz * sA;
    const u16* B = B_ + (size_t)bz * sB;

    // 32 KiB union: K-loop uses As|Bs halves; EPI2 v-mode reuses all of it
    // as a 128x128 fp16 transpose buffer after the final barrier.
    __shared__ __align__(16) u16 sh[16384];
    u16* As = sh;
    u16* Bs = sh + 8192;

    const int r0 = tid >> 3;
    const int c0 = ((tid & 7) ^ (r0 & 7)) * 8;
    size_t aoff[4], boff[4];
#pragma unroll
    for (int j = 0; j < 4; j++) {
        aoff[j] = (size_t)(m0 + r0 + j * 32) * lda + c0;
        boff[j] = (size_t)(n0 + r0 + j * 32) * ldb + c0;
    }
    const int g7 = l31 & 7;
    const int rowA0 = (bm + l31) * 64, rowA1 = (bm + 32 + l31) * 64;
    const int rowB0 = (bn + l31) * 64, rowB1 = (bn + 32 + l31) * 64;

    f32x16 acc[2][2];
#pragma unroll
    for (int i = 0; i < 2; i++)
#pragma unroll
        for (int j = 0; j < 2; j++)
#pragma unroll
            for (int r = 0; r < 16; r++) acc[i][j][r] = 0.f;

    for (int k0 = 0; k0 < K; k0 += 64) {
#pragma unroll
        for (int j = 0; j < 4; j++) {
            gl16(A + aoff[j] + k0, As + j * 2048 + wav * 512);
            gl16(B + boff[j] + k0, Bs + j * 2048 + wav * 512);
        }
        __syncthreads();

#pragma unroll
        for (int h = 0; h < 4; h++) {
            const int so = ((h * 2 + lh) ^ g7) * 8;
            f16x8 af[2], bfr[2];
            af[0] = *(const f16x8*)&As[rowA0 + so];
            af[1] = *(const f16x8*)&As[rowA1 + so];
            bfr[0] = *(const f16x8*)&Bs[rowB0 + so];
            bfr[1] = *(const f16x8*)&Bs[rowB1 + so];
#pragma unroll
            for (int i = 0; i < 2; i++)
#pragma unroll
                for (int j = 0; j < 2; j++)
                    acc[i][j] = mfma16(af[i], bfr[j], acc[i][j]);
        }
        __syncthreads();
    }

    // ---- epilogue: 32x32 C/D layout col=lane&31, row=(r&3)+8*(r>>2)+4*lh ----
    if (EPI == 2) {
        const int mode = bx >> 2;   // 0=q 1=k 2=v (logical bx)
        if (mode == 2) {
            // v: transpose 128x128 tile through LDS, coalesced vT stores.
#pragma unroll
            for (int it = 0; it < 2; it++)
#pragma unroll
                for (int jt = 0; jt < 2; jt++) {
                    const int lc = bn + jt * 32 + l31;          // 0..127
                    const float badd = biasf[n0 + lc];
#pragma unroll
                    for (int r = 0; r < 16; r++) {
                        const int row = bm + it * 32 + (r & 3) + 8 * (r >> 2) + 4 * lh;
                        sh[lc * 128 + (row ^ ((lc & 15) << 3))] =
                            f2h(acc[it][jt][r] + badd);
                    }
                }
            __syncthreads();
            const int vbase = n0 - 1024;                        // v col offset
#pragma unroll
            for (int p = 0; p < 8; p++) {
                const int q = p * 256 + tid;                    // 0..2047
                const int lc = q >> 4, ch = q & 15;
                const int g = ch ^ (lc & 15);
                f16x8 val = *(const f16x8*)&sh[lc * 128 + g * 8];
                *(f16x8*)&OvT[(size_t)(vbase + lc) * 16384 + m0 + ch * 8] = val;
            }
        } else {
#pragma unroll
            for (int it = 0; it < 2; it++)
#pragma unroll
                for (int jt = 0; jt < 2; jt++) {
                    const int gcol = n0 + bn + jt * 32 + l31;
                    const int lcol = gcol & 511;
                    const float badd = biasf[gcol];
#pragma unroll
                    for (int r = 0; r < 16; r++) {
                        const int row = m0 + bm + it * 32 + (r & 3) + 8 * (r >> 2) + 4 * lh;
                        const float v = acc[it][jt][r] + badd;
                        if (mode == 0) Oq[(size_t)row * 512 + lcol] = f2h(v);
                        else           Ok[(size_t)row * 512 + lcol] = f2h(v);
                    }
                }
        }
    } else if (EPI == 0) {
        // scores: compact fp16 arena (halves the mandatory write bytes).
        u16* Ch = (u16*)Cp;
        const long coff = (long)bz * sC;
#pragma unroll
        for (int it = 0; it < 2; it++)
#pragma unroll
            for (int jt = 0; jt < 2; jt++) {
                const int col = n0 + bn + jt * 32 + l31;
#pragma unroll
                for (int r = 0; r < 16; r++) {
                    const int row = m0 + bm + it * 32 + (r & 3) + 8 * (r >> 2) + 4 * lh;
                    Ch[(size_t)(coff + (long)row * ldc + col)] = f2h(acc[it][jt][r]);
                }
            }
    } else {
        const int isbf = *flagp;
        float* Cf = (float*)Cp;
        u16* Cb = (u16*)Cp;
        const long coff = cbase + (long)bz * sC;
#pragma unroll
        for (int it = 0; it < 2; it++)
#pragma unroll
            for (int jt = 0; jt < 2; jt++) {
                const int col = n0 + bn + jt * 32 + l31;
#pragma unroll
                for (int r = 0; r < 16; r++) {
                    const int row = m0 + bm + it * 32 + (r & 3) + 8 * (r >> 2) + 4 * lh;
                    const size_t idx = (size_t)(coff + (long)row * ldc + col);
                    if (isbf) Cb[idx] = f2bf(acc[it][jt][r]);
                    else Cf[idx] = acc[it][jt][r];
                }
            }
    }
}

// ---- softmax: fp16 row -> fp16 P in place (compact u16 arena) ----
__global__ __launch_bounds__(256) void softmax_k(u16* __restrict__ sc)
{
    u16* srow = sc + (size_t)blockIdx.x * S_LEN;
    const int tid = threadIdx.x;

    f16x8 v = ((const f16x8*)srow)[tid];
    float f[8];
#pragma unroll
    for (int j = 0; j < 8; j++) f[j] = (float)v[j];

    float m = f[0];
#pragma unroll
    for (int j = 1; j < 8; j++) m = fmaxf(m, f[j]);
#pragma unroll
    for (int off = 32; off > 0; off >>= 1) m = fmaxf(m, __shfl_down(m, off));

    __shared__ float redm[4], reds[4];
    if ((tid & 63) == 0) redm[tid >> 6] = m;
    __syncthreads();
    m = fmaxf(fmaxf(redm[0], redm[1]), fmaxf(redm[2], redm[3]));

    float s = 0.f;
#pragma unroll
    for (int j = 0; j < 8; j++) { f[j] = __expf(f[j] - m); s += f[j]; }
#pragma unroll
    for (int off = 32; off > 0; off >>= 1) s += __shfl_down(s, off);
    if ((tid & 63) == 0) reds[tid >> 6] = s;
    __syncthreads();
    s = reds[0] + reds[1] + reds[2] + reds[3];

    const float inv = 1.0f / s;
    f16x8 p;
#pragma unroll
    for (int j = 0; j < 8; j++) p[j] = (_Float16)(f[j] * inv);
    ((f16x8*)srow)[tid] = p;
}

extern "C" void kernel_launch(void* const* d_in, const int* in_sizes, int n_in,
                              void* d_out, int out_size, void* d_ws, size_t ws_size,
                              hipStream_t stream)
{
    const void* x  = d_in[0];
    const void* Wq = d_in[1]; const void* bq = d_in[2];
    const void* Wk = d_in[3]; const void* bk = d_in[4];
    const void* Wv = d_in[5]; const void* bv = d_in[6];

    const int S = S_LEN, D = D_DIM;
    const long SD = (long)S * D;                      // 1,048,576

    char* w = (char*)d_ws;
    int*   flag = (int*)w;                            // @0
    u16*   WT   = (u16*)(w + 1024);                   // 1,572,864
    float* bcat = (float*)(w + 1573888);              // 6,144
    u16*   xf   = (u16*)(w + 1580032);                // 16,777,216
    u16*   qf   = (u16*)(w + 18357248);
    u16*   kf   = (u16*)(w + 35134464);
    u16*   vT   = (u16*)(w + 51911680);               // [512][16384]
    u16*   scP  = (u16*)(w + 68688896);               // fp16 scores arena

    const size_t avail = ws_size > 68688896ull ? ws_size - 68688896ull : 0;
    const size_t perb = (size_t)S * S * 2;            // fp16 now
    const int c = avail >= 8 * perb ? 8 : avail >= 4 * perb ? 4 : avail >= 2 * perb ? 2 : 1;

    dim3 blk(256);

    detect_k<<<1, 64, 0, stream>>>((const u16*)x, flag);
    cvt_x<<<8192, blk, 0, stream>>>(x, xf, flag);
    pack_w<<<dim3(512, 6), blk, 0, stream>>>(Wq, Wk, Wv, WT, flag);
    pack_bias<<<6, blk, 0, stream>>>(bq, bk, bv, bcat, flag);

    // fused q|k|v projection: [16384,512] x [512,1536]^T(packed WT)
    gemm_f16<2><<<dim3(12, 128, 1), blk, 0, stream>>>(
        xf, WT, nullptr, bcat, qf, kf, vT, flag,
        512, 512, 512, 0, 0, 0, 0, 0);

    for (int cb = 0; cb < B_N; cb += c) {
        const size_t off = (size_t)cb * SD;
        // scores = q k^T (fp16 compact)
        gemm_f16<0><<<dim3(16, 16, c), blk, 0, stream>>>(
            qf + off, kf + off, scP, nullptr, nullptr, nullptr, nullptr, flag,
            512, 512, 512, S, SD, SD, (long)S * S, 0);
        softmax_k<<<c * S, blk, 0, stream>>>(scP);
        // out = P @ v via vT rows; P fp16 compact (lda = S)
        gemm_f16<1><<<dim3(4, 16, c), blk, 0, stream>>>(
            scP, vT + (size_t)cb * S, d_out, nullptr,
            nullptr, nullptr, nullptr, flag,
            S, S, B_N * S, D, (long)S * S, S, SD, (long)cb * SD);
    }
}

// Round 13
// 251.477 us; speedup vs baseline: 1.1470x; 1.0028x over previous
//
#include <hip/hip_runtime.h>
#include <hip/hip_fp16.h>

// Self-attention B=8 S=2048 D=512, fp32-vs-bf16 input auto-detect.
// R21 = R20 (252.2 us best) + PV occupancy fix. R20 counters: top dispatch
// is PV (WRITE=33.5MB=out), 59us @ 16% HBM / 22% MFMA -- latency-bound
// with only 512 blocks (2/CU) vs scores' 2048 (5/CU, 45us same FLOPs).
// Fix: dedicated gemm_pv64: BM=64 x BN=128, 256 thr / 4 waves of 32x64,
// 16x16x32 frags (R11/R18 HW-verified conflict-free XOR reads -> kills
// PV's 4.2M bank conflicts too), LDS 24KB -> grid 1024 = 4 blocks/CU.
// Same m97 2-barrier loop + z-fold swizzle (total=128c %8==0).
// History: R13 xy-swz +10; R14 v-transpose +10; R15/R19 z-fold; R20 fp16
// scores -22; R9/R11/R12/R16/R18 schedule experiments regressed->reverted.

typedef unsigned short u16;
typedef unsigned int u32;
typedef __attribute__((ext_vector_type(8))) _Float16 f16x8;
typedef __attribute__((ext_vector_type(16))) float f32x16;
typedef __attribute__((ext_vector_type(4))) float f32x4;

#define S_LEN 2048
#define D_DIM 512
#define B_N 8

__device__ __forceinline__ u16 f2bf(float f) {
    u32 u = __float_as_uint(f);
    u32 r = u + 0x7FFFu + ((u >> 16) & 1u);   // RNE
    return (u16)(r >> 16);
}
__device__ __forceinline__ float bf2f(u16 h) {
    return __uint_as_float((u32)h << 16);
}
__device__ __forceinline__ u16 f2h(float f) {
    _Float16 h = (_Float16)f;                 // RNE
    return *(u16*)&h;
}
__device__ __forceinline__ void gl16(const u16* g, u16* l) {
    __builtin_amdgcn_global_load_lds(
        (const __attribute__((address_space(1))) void*)g,
        (__attribute__((address_space(3))) void*)l, 16, 0, 0);
}
__device__ __forceinline__ f32x16 mfma16(f16x8 a, f16x8 b, f32x16 c) {
    return __builtin_amdgcn_mfma_f32_32x32x16_f16(a, b, c, 0, 0, 0);
}
__device__ __forceinline__ f32x4 mfma16q(f16x8 a, f16x8 b, f32x4 c) {
    return __builtin_amdgcn_mfma_f32_16x16x32_f16(a, b, c, 0, 0, 0);
}

// ---- dtype detector ----
__global__ void detect_k(const u16* __restrict__ x, int* __restrict__ flag)
{
    int t = threadIdx.x;
    u16 u = x[2 * t];
    int e = (u >> 7) & 0xFF;
    int sane = (e == 0) || (e >= 110 && e <= 140);
    unsigned long long b = __ballot(sane);
    if (t == 0) *flag = (__popcll(b) >= 32) ? 1 : 0;
}

// ---- convert x to fp16 ----
__global__ __launch_bounds__(256) void cvt_x(
    const void* __restrict__ X, u16* __restrict__ xf,
    const int* __restrict__ flagp)
{
    const size_t i4 = ((size_t)blockIdx.x * 256 + threadIdx.x) * 4;
    float f[4];
    if (*flagp) {
        ushort4 u = *(const ushort4*)((const u16*)X + i4);
        f[0] = bf2f(u.x); f[1] = bf2f(u.y); f[2] = bf2f(u.z); f[3] = bf2f(u.w);
    } else {
        float4 ff = *(const float4*)((const float*)X + i4);
        f[0] = ff.x; f[1] = ff.y; f[2] = ff.z; f[3] = ff.w;
    }
    ushort4 h;
    h.x = f2h(f[0]); h.y = f2h(f[1]); h.z = f2h(f[2]); h.w = f2h(f[3]);
    *(ushort4*)(xf + i4) = h;
}

// ---- pack W^T concat (q|k|v) fp16: WT[n 0..1535][k 0..511] ----
__global__ __launch_bounds__(256) void pack_w(
    const void* __restrict__ Wq, const void* __restrict__ Wk, const void* __restrict__ Wv,
    u16* __restrict__ WT, const int* __restrict__ flagp)
{
    const int k = blockIdx.x;
    const int n = blockIdx.y * 256 + threadIdx.x;
    const void* W = n < 512 ? Wq : n < 1024 ? Wk : Wv;
    const int nc = n & 511;
    float f = *flagp ? bf2f(((const u16*)W)[(size_t)k * 512 + nc])
                     : ((const float*)W)[(size_t)k * 512 + nc];
    WT[(size_t)n * 512 + k] = f2h(f);
}

__global__ void pack_bias(
    const void* __restrict__ bq, const void* __restrict__ bk, const void* __restrict__ bv,
    float* __restrict__ bcat, const int* __restrict__ flagp)
{
    const int t = blockIdx.x * 256 + threadIdx.x;
    const void* b = t < 512 ? bq : t < 1024 ? bk : bv;
    const int i = t & 511;
    bcat[t] = *flagp ? bf2f(((const u16*)b)[i]) : ((const float*)b)[i];
}

// ---- unified fp16 BT-GEMM: C[M,N] = A[M,K] * B[N,K]^T ----
// 128x128 tile, BK=64. Staging: slot s of row r holds global chunk s^(r&7).
// z-fold chunked XCD swizzle on ALL paths (total%8==0 at all call sites).
// EPI 0: fp16 C (scores, compact u16 arena). EPI 2: proj q|k|vT +bias.
template <int EPI>
__global__ __launch_bounds__(256) void gemm_f16(
    const u16* __restrict__ A_, const u16* __restrict__ B_,
    void* __restrict__ Cp, const float* __restrict__ biasf,
    u16* __restrict__ Oq, u16* __restrict__ Ok, u16* __restrict__ OvT,
    const int* __restrict__ flagp,
    int K, int lda, int ldb, int ldc, long sA, long sB, long sC, long cbase)
{
    const int tid = threadIdx.x;
    const int lane = tid & 63, wav = tid >> 6;
    const int l31 = lane & 31, lh = lane >> 5;

    // ---- XCD-aware chunked swizzle of the z-major linear id ----
    const int gx = gridDim.x, gy = gridDim.y;
    const int total = gx * gy * gridDim.z;
    const int chunk = total >> 3;              // total % 8 == 0
    int lin = (blockIdx.z * gy + blockIdx.y) * gx + blockIdx.x;
    lin = (lin & 7) * chunk + (lin >> 3);
    const int bx = lin % gx;
    const int by = (lin / gx) % gy;
    const int bz = lin / (gx * gy);

    const int m0 = by * 128, n0 = bx * 128;
    const int bm = (wav >> 1) * 64, bn = (wav & 1) * 64;

    const u16* A = A_ + (size_t)bz * sA;
    const u16* B = B_ + (size_t)bz * sB;

    // 32 KiB union: K-loop uses As|Bs halves; EPI2 v-mode reuses all of it
    // as a 128x128 fp16 transpose buffer after the final barrier.
    __shared__ __align__(16) u16 sh[16384];
    u16* As = sh;
    u16* Bs = sh + 8192;

    const int r0 = tid >> 3;
    const int c0 = ((tid & 7) ^ (r0 & 7)) * 8;
    size_t aoff[4], boff[4];
#pragma unroll
    for (int j = 0; j < 4; j++) {
        aoff[j] = (size_t)(m0 + r0 + j * 32) * lda + c0;
        boff[j] = (size_t)(n0 + r0 + j * 32) * ldb + c0;
    }
    const int g7 = l31 & 7;
    const int rowA0 = (bm + l31) * 64, rowA1 = (bm + 32 + l31) * 64;
    const int rowB0 = (bn + l31) * 64, rowB1 = (bn + 32 + l31) * 64;

    f32x16 acc[2][2];
#pragma unroll
    for (int i = 0; i < 2; i++)
#pragma unroll
        for (int j = 0; j < 2; j++)
#pragma unroll
            for (int r = 0; r < 16; r++) acc[i][j][r] = 0.f;

    for (int k0 = 0; k0 < K; k0 += 64) {
#pragma unroll
        for (int j = 0; j < 4; j++) {
            gl16(A + aoff[j] + k0, As + j * 2048 + wav * 512);
            gl16(B + boff[j] + k0, Bs + j * 2048 + wav * 512);
        }
        __syncthreads();

#pragma unroll
        for (int h = 0; h < 4; h++) {
            const int so = ((h * 2 + lh) ^ g7) * 8;
            f16x8 af[2], bfr[2];
            af[0] = *(const f16x8*)&As[rowA0 + so];
            af[1] = *(const f16x8*)&As[rowA1 + so];
            bfr[0] = *(const f16x8*)&Bs[rowB0 + so];
            bfr[1] = *(const f16x8*)&Bs[rowB1 + so];
#pragma unroll
            for (int i = 0; i < 2; i++)
#pragma unroll
                for (int j = 0; j < 2; j++)
                    acc[i][j] = mfma16(af[i], bfr[j], acc[i][j]);
        }
        __syncthreads();
    }

    // ---- epilogue: 32x32 C/D layout col=lane&31, row=(r&3)+8*(r>>2)+4*lh ----
    if (EPI == 2) {
        const int mode = bx >> 2;   // 0=q 1=k 2=v (logical bx)
        if (mode == 2) {
            // v: transpose 128x128 tile through LDS, coalesced vT stores.
#pragma unroll
            for (int it = 0; it < 2; it++)
#pragma unroll
                for (int jt = 0; jt < 2; jt++) {
                    const int lc = bn + jt * 32 + l31;          // 0..127
                    const float badd = biasf[n0 + lc];
#pragma unroll
                    for (int r = 0; r < 16; r++) {
                        const int row = bm + it * 32 + (r & 3) + 8 * (r >> 2) + 4 * lh;
                        sh[lc * 128 + (row ^ ((lc & 15) << 3))] =
                            f2h(acc[it][jt][r] + badd);
                    }
                }
            __syncthreads();
            const int vbase = n0 - 1024;                        // v col offset
#pragma unroll
            for (int p = 0; p < 8; p++) {
                const int q = p * 256 + tid;                    // 0..2047
                const int lc = q >> 4, ch = q & 15;
                const int g = ch ^ (lc & 15);
                f16x8 val = *(const f16x8*)&sh[lc * 128 + g * 8];
                *(f16x8*)&OvT[(size_t)(vbase + lc) * 16384 + m0 + ch * 8] = val;
            }
        } else {
#pragma unroll
            for (int it = 0; it < 2; it++)
#pragma unroll
                for (int jt = 0; jt < 2; jt++) {
                    const int gcol = n0 + bn + jt * 32 + l31;
                    const int lcol = gcol & 511;
                    const float badd = biasf[gcol];
#pragma unroll
                    for (int r = 0; r < 16; r++) {
                        const int row = m0 + bm + it * 32 + (r & 3) + 8 * (r >> 2) + 4 * lh;
                        const float v = acc[it][jt][r] + badd;
                        if (mode == 0) Oq[(size_t)row * 512 + lcol] = f2h(v);
                        else           Ok[(size_t)row * 512 + lcol] = f2h(v);
                    }
                }
        }
    } else {
        // scores: compact fp16 arena (halves the mandatory write bytes).
        u16* Ch = (u16*)Cp;
        const long coff = (long)bz * sC;
#pragma unroll
        for (int it = 0; it < 2; it++)
#pragma unroll
            for (int jt = 0; jt < 2; jt++) {
                const int col = n0 + bn + jt * 32 + l31;
#pragma unroll
                for (int r = 0; r < 16; r++) {
                    const int row = m0 + bm + it * 32 + (r & 3) + 8 * (r >> 2) + 4 * lh;
                    Ch[(size_t)(coff + (long)row * ldc + col)] = f2h(acc[it][jt][r]);
                }
            }
    }
}

// ---- PV GEMM, occupancy-tuned: C[M,N] = P[M,K] * vT[N,K]^T ----
// BM=64 x BN=128, BK=64, 256 thr / 4 waves (2M x 2N), each wave 32x64 of
// 16x16x32 frags (XOR reads conflict-free, HW-verified R11/R18).
// LDS 24KB -> 6 blocks/CU allocatable; grid (4,32,c)=1024 -> 4/CU resident.
__global__ __launch_bounds__(256) void gemm_pv64(
    const u16* __restrict__ A_, const u16* __restrict__ B_,
    void* __restrict__ Cp, const int* __restrict__ flagp,
    int K, int lda, int ldb, int ldc, long sA, long sB, long sC, long cbase)
{
    const int tid = threadIdx.x;
    const int lane = tid & 63;
    const int wid = tid >> 6;            // 0..3
    const int wm = wid & 1;              // M half (32 rows)
    const int wn = wid >> 1;             // N half (64 cols)
    const int l15 = lane & 15, lq = lane >> 4;

    // z-fold chunked XCD swizzle (total = 128c, % 8 == 0 for c in {1,2,4,8})
    const int gx = gridDim.x, gy = gridDim.y;
    const int total = gx * gy * gridDim.z;
    const int chunk = total >> 3;
    int lin = (blockIdx.z * gy + blockIdx.y) * gx + blockIdx.x;
    lin = (lin & 7) * chunk + (lin >> 3);
    const int bx = lin % gx;
    const int by = (lin / gx) % gy;
    const int bz = lin / (gx * gy);

    const int m0 = by * 64, n0 = bx * 128;

    const u16* A = A_ + (size_t)bz * sA;
    const u16* B = B_ + (size_t)bz * sB;

    __shared__ __align__(16) u16 As[64 * 64];    //  8 KiB
    __shared__ __align__(16) u16 Bs[128 * 64];   // 16 KiB

    // staging: thread t loads 16B; r0 = t>>3 in 0..31, slot t&7 = chunk^(r&7)
    const int r0 = tid >> 3;
    const int c0 = ((tid & 7) ^ (r0 & 7)) * 8;
    size_t aoff[2], boff[4];
#pragma unroll
    for (int j = 0; j < 2; j++)
        aoff[j] = (size_t)(m0 + j * 32 + r0) * lda + c0;
#pragma unroll
    for (int j = 0; j < 4; j++)
        boff[j] = (size_t)(n0 + j * 32 + r0) * ldb + c0;

    f32x4 acc[2][4];
#pragma unroll
    for (int h = 0; h < 2; h++)
#pragma unroll
        for (int nj = 0; nj < 4; nj++)
#pragma unroll
            for (int r = 0; r < 4; r++) acc[h][nj][r] = 0.f;

    for (int k0 = 0; k0 < K; k0 += 64) {
#pragma unroll
        for (int j = 0; j < 2; j++)
            gl16(A + aoff[j] + k0, As + j * 2048 + (tid & 63) * 8 + (tid >> 6) * 512);
#pragma unroll
        for (int j = 0; j < 4; j++)
            gl16(B + boff[j] + k0, Bs + j * 2048 + (tid & 63) * 8 + (tid >> 6) * 512);
        __syncthreads();

#pragma unroll
        for (int ks = 0; ks < 2; ks++) {
            f16x8 a[2], b[4];
#pragma unroll
            for (int h = 0; h < 2; h++) {
                const int row = wm * 32 + h * 16 + l15;
                const int off = (row << 6) + ((((ks << 2) + lq) ^ (row & 7)) << 3);
                a[h] = *(const f16x8*)&As[off];
            }
#pragma unroll
            for (int nj = 0; nj < 4; nj++) {
                const int row = wn * 64 + nj * 16 + l15;
                const int off = (row << 6) + ((((ks << 2) + lq) ^ (row & 7)) << 3);
                b[nj] = *(const f16x8*)&Bs[off];
            }
#pragma unroll
            for (int h = 0; h < 2; h++)
#pragma unroll
                for (int nj = 0; nj < 4; nj++)
                    acc[h][nj] = mfma16q(a[h], b[nj], acc[h][nj]);
        }
        __syncthreads();
    }

    // ---- epilogue: 16x16 C/D layout col=lane&15, row=(lane>>4)*4+reg ----
    const int isbf = *flagp;
    float* Cf = (float*)Cp;
    u16* Cb = (u16*)Cp;
    const long coff = cbase + (long)bz * sC;
#pragma unroll
    for (int h = 0; h < 2; h++)
#pragma unroll
        for (int nj = 0; nj < 4; nj++) {
            const int col = n0 + wn * 64 + nj * 16 + l15;
#pragma unroll
            for (int r = 0; r < 4; r++) {
                const int row = m0 + wm * 32 + h * 16 + lq * 4 + r;
                const size_t idx = (size_t)(coff + (long)row * ldc + col);
                if (isbf) Cb[idx] = f2bf(acc[h][nj][r]);
                else Cf[idx] = acc[h][nj][r];
            }
        }
}

// ---- softmax: fp16 row -> fp16 P in place (compact u16 arena) ----
__global__ __launch_bounds__(256) void softmax_k(u16* __restrict__ sc)
{
    u16* srow = sc + (size_t)blockIdx.x * S_LEN;
    const int tid = threadIdx.x;

    f16x8 v = ((const f16x8*)srow)[tid];
    float f[8];
#pragma unroll
    for (int j = 0; j < 8; j++) f[j] = (float)v[j];

    float m = f[0];
#pragma unroll
    for (int j = 1; j < 8; j++) m = fmaxf(m, f[j]);
#pragma unroll
    for (int off = 32; off > 0; off >>= 1) m = fmaxf(m, __shfl_down(m, off));

    __shared__ float redm[4], reds[4];
    if ((tid & 63) == 0) redm[tid >> 6] = m;
    __syncthreads();
    m = fmaxf(fmaxf(redm[0], redm[1]), fmaxf(redm[2], redm[3]));

    float s = 0.f;
#pragma unroll
    for (int j = 0; j < 8; j++) { f[j] = __expf(f[j] - m); s += f[j]; }
#pragma unroll
    for (int off = 32; off > 0; off >>= 1) s += __shfl_down(s, off);
    if ((tid & 63) == 0) reds[tid >> 6] = s;
    __syncthreads();
    s = reds[0] + reds[1] + reds[2] + reds[3];

    const float inv = 1.0f / s;
    f16x8 p;
#pragma unroll
    for (int j = 0; j < 8; j++) p[j] = (_Float16)(f[j] * inv);
    ((f16x8*)srow)[tid] = p;
}

extern "C" void kernel_launch(void* const* d_in, const int* in_sizes, int n_in,
                              void* d_out, int out_size, void* d_ws, size_t ws_size,
                              hipStream_t stream)
{
    const void* x  = d_in[0];
    const void* Wq = d_in[1]; const void* bq = d_in[2];
    const void* Wk = d_in[3]; const void* bk = d_in[4];
    const void* Wv = d_in[5]; const void* bv = d_in[6];

    const int S = S_LEN, D = D_DIM;
    const long SD = (long)S * D;                      // 1,048,576

    char* w = (char*)d_ws;
    int*   flag = (int*)w;                            // @0
    u16*   WT   = (u16*)(w + 1024);                   // 1,572,864
    float* bcat = (float*)(w + 1573888);              // 6,144
    u16*   xf   = (u16*)(w + 1580032);                // 16,777,216
    u16*   qf   = (u16*)(w + 18357248);
    u16*   kf   = (u16*)(w + 35134464);
    u16*   vT   = (u16*)(w + 51911680);               // [512][16384]
    u16*   scP  = (u16*)(w + 68688896);               // fp16 scores arena

    const size_t avail = ws_size > 68688896ull ? ws_size - 68688896ull : 0;
    const size_t perb = (size_t)S * S * 2;            // fp16
    const int c = avail >= 8 * perb ? 8 : avail >= 4 * perb ? 4 : avail >= 2 * perb ? 2 : 1;

    dim3 blk(256);

    detect_k<<<1, 64, 0, stream>>>((const u16*)x, flag);
    cvt_x<<<8192, blk, 0, stream>>>(x, xf, flag);
    pack_w<<<dim3(512, 6), blk, 0, stream>>>(Wq, Wk, Wv, WT, flag);
    pack_bias<<<6, blk, 0, stream>>>(bq, bk, bv, bcat, flag);

    // fused q|k|v projection: [16384,512] x [512,1536]^T(packed WT)
    gemm_f16<2><<<dim3(12, 128, 1), blk, 0, stream>>>(
        xf, WT, nullptr, bcat, qf, kf, vT, flag,
        512, 512, 512, 0, 0, 0, 0, 0);

    for (int cb = 0; cb < B_N; cb += c) {
        const size_t off = (size_t)cb * SD;
        // scores = q k^T (fp16 compact)
        gemm_f16<0><<<dim3(16, 16, c), blk, 0, stream>>>(
            qf + off, kf + off, scP, nullptr, nullptr, nullptr, nullptr, flag,
            512, 512, 512, S, SD, SD, (long)S * S, 0);
        softmax_k<<<c * S, blk, 0, stream>>>(scP);
        // out = P @ v via vT rows; P fp16 compact (lda = S); BM=64 tiles
        gemm_pv64<<<dim3(4, 32, c), blk, 0, stream>>>(
            scP, vT + (size_t)cb * S, d_out, flag,
            S, S, B_N * S, D, (long)S * S, S, SD, (long)cb * SD);
    }
}